// Round 3
// baseline (4195.486 us; speedup 1.0000x reference)
//
#include <hip/hip_runtime.h>
#include <stdint.h>

#define MB 16   // batch rows per group
#define GW 16   // workgroups per group
#define NU 32   // hidden units per WG
#define HD 512
#define SEQ 512
#define DX 40
#define HB 8    // rows per pipeline half

using short8 = __attribute__((ext_vector_type(8))) short;
using f32x4  = __attribute__((ext_vector_type(4))) float;

__device__ __forceinline__ unsigned short f2bf(float f) {
  uint32_t u = __builtin_bit_cast(uint32_t, f);
  u += 0x7fffu + ((u >> 16) & 1u);
  return (unsigned short)(u >> 16);
}
__device__ __forceinline__ float sigm(float x) { return 1.0f / (1.0f + __expf(-x)); }

#define MFMA_B16(a, b, c) __builtin_amdgcn_mfma_f32_16x16x32_bf16((a), (b), (c), 0, 0, 0)

// h exchange protocol (R6 == R5 resubmit; R5 bench was an infra failure):
//  - 16 batch rows per group split into halves A(0-7)/B(8-15) — independent
//    recurrent chains, processed on alternating sub-steps, software-pipelined
//    so each half's h-publication LLC round trip hides under the other
//    half's compute sub-step.
//  - Per sub-step (half H, other O): MFMA gates(H); sync C; poll O's
//    producer flags (set one sub-step ago -> usually immediate) + issue O's
//    h loads; elementwise(H) + publish h(H) while loads fly; sync D (drains
//    vmcnt -> h committed at LLC); tid0 flag store; stage O into LDS; sync B.
//  - h words: bf16x2 u32, relaxed AGENT atomics (write-through to LLC).
//  - fused poll: each thread's 2x8B chunks come from ONE producer WG
//    ((tid&127)>>3) -> 16 coalesced flag lines per (group, half).
//  - Deadlock-free: flag values are monotone, dependencies flow forward in
//    time only. Overwrite-safe: producer reaching write of buffer parity p
//    has polled all 16 WGs past the sub-step whose reads of p precede their
//    flag stores (2-deep induction, both halves).

// ---------------- GRU persistent kernel ----------------
__global__ __launch_bounds__(512, 1) void gru_kernel(
    const float* __restrict__ x, const float* __restrict__ Wih,
    const float* __restrict__ Whh, const float* __restrict__ bih,
    const float* __restrict__ bhh, unsigned* __restrict__ flags,
    uint32_t* __restrict__ hbuf, float* __restrict__ o1,
    float* __restrict__ stats)
{
  const int wg = blockIdx.x & (GW - 1);
  const int g  = blockIdx.x >> 4;
  const int tid = threadIdx.x;
  const int wave = tid >> 6;
  const int lane = tid & 63;
  const int u0 = wg * NU;
  const int bg = g * MB;

  __shared__ __align__(16) unsigned short h_s[2][HB][520];
  __shared__ __align__(16) unsigned short x_s[2][HB][72];  // 40..63 zero pad
  __shared__ float gate_s[3][HB][NU];
  __shared__ float xn_s[HB][NU];

  // weight B-fragments in registers. B[k][n]: n=lane&15, k=(lane>>4)*8+j.
  short8 bfrag[18];
  const int myGate = wave >> 1;
  const int ut = wave & 1;
  const int kq = (lane >> 4) * 8;
  if (wave < 6) {
    const int row = myGate * HD + u0 + ut * 16 + (lane & 15);
    for (int kt = 0; kt < 16; ++kt) {
      const float* p = Whh + (size_t)row * HD + kt * 32 + kq;
      short8 f;
#pragma unroll
      for (int j = 0; j < 8; ++j) f[j] = (short)f2bf(p[j]);
      bfrag[kt] = f;
    }
    for (int kt = 16; kt < 18; ++kt) {     // x cols: r,z only (n via xn MFMA)
      short8 f;
#pragma unroll
      for (int j = 0; j < 8; ++j) {
        int c = kt * 32 + kq + j - HD;
        float v = (myGate < 2 && c < DX) ? Wih[(size_t)row * DX + c] : 0.0f;
        f[j] = (short)f2bf(v);
      }
      bfrag[kt] = f;
    }
  } else {                                 // waves 6,7: Wn fragments, K=64 pad
    const int row = 2 * HD + u0 + (wave - 6) * 16 + (lane & 15);
    for (int kt = 0; kt < 2; ++kt) {
      short8 f;
#pragma unroll
      for (int j = 0; j < 8; ++j) {
        int c = kt * 32 + kq + j;
        f[j] = (short)((c < DX) ? f2bf(Wih[(size_t)row * DX + c]) : 0);
      }
      bfrag[kt] = f;
    }
  }

  const int sb = tid >> 5;   // half-local row (valid for tid<256)
  const int su = tid & 31;
  float hprevA = 0.f, hprevB = 0.f, ssum = 0.f, ssq = 0.f;
  const float b_r  = bih[u0 + su] + bhh[u0 + su];
  const float b_z  = bih[HD + u0 + su] + bhh[HD + u0 + su];
  const float b_in = bih[2 * HD + u0 + su];
  const float b_hn = bhh[2 * HD + u0 + su];

  unsigned* flagA = flags + (size_t)(g * 2 + 0) * GW * 16;  // 64B-strided
  unsigned* flagB = flags + (size_t)(g * 2 + 1) * GW * 16;
  const int prodIdx = (tid & 127) >> 3;    // producer WG of this thread's chunks

  // prologue: zero x pads, stage half A h(0)=0 and x(0)
  if (tid < 288) ((unsigned long long*)x_s)[tid] = 0ull;
  __syncthreads();
  {
    *(unsigned long long*)(&h_s[0][tid >> 7][(tid & 127) * 4]) = 0ull;
    int q = 512 + tid;
    *(unsigned long long*)(&h_s[0][q >> 7][(q & 127) * 4]) = 0ull;
    if (lane < 40)
      x_s[0][wave][lane] = f2bf(x[((size_t)(bg + wave) * SEQ) * DX + lane]);
  }
  __syncthreads();

#define GRU_SUB(H, O, T, TP, HPREV)                                           \
  do {                                                                        \
    if (wave < 6) {                                                           \
      const int m = lane & 7;                                                 \
      f32x4 a0 = {0.f, 0.f, 0.f, 0.f}, a1 = {0.f, 0.f, 0.f, 0.f};             \
      _Pragma("unroll")                                                       \
      for (int kt = 0; kt < 16; kt += 2) {                                    \
        short8 ha0 = *(const short8*)(&h_s[H][m][kt * 32 + kq]);              \
        short8 ha1 = *(const short8*)(&h_s[H][m][(kt + 1) * 32 + kq]);        \
        a0 = MFMA_B16(ha0, bfrag[kt], a0);                                    \
        a1 = MFMA_B16(ha1, bfrag[kt + 1], a1);                                \
      }                                                                       \
      short8 ax0 = *(const short8*)(&x_s[H][m][kq]);                          \
      short8 ax1 = *(const short8*)(&x_s[H][m][32 + kq]);                     \
      a0 = MFMA_B16(ax0, bfrag[16], a0);                                      \
      a1 = MFMA_B16(ax1, bfrag[17], a1);                                      \
      f32x4 acc = a0 + a1;                                                    \
      if (lane < 32) {                                                        \
        _Pragma("unroll")                                                     \
        for (int r = 0; r < 4; ++r)                                           \
          gate_s[myGate][(lane >> 4) * 4 + r][ut * 16 + (lane & 15)] = acc[r];\
      }                                                                       \
    } else {                                                                  \
      const int m = lane & 7;                                                 \
      f32x4 acc = {0.f, 0.f, 0.f, 0.f};                                       \
      short8 ax0 = *(const short8*)(&x_s[H][m][kq]);                          \
      short8 ax1 = *(const short8*)(&x_s[H][m][32 + kq]);                     \
      acc = MFMA_B16(ax0, bfrag[0], acc);                                     \
      acc = MFMA_B16(ax1, bfrag[1], acc);                                     \
      if (lane < 32) {                                                        \
        _Pragma("unroll")                                                     \
        for (int r = 0; r < 4; ++r)                                           \
          xn_s[(lane >> 4) * 4 + r][(wave - 6) * 16 + (lane & 15)] = acc[r];  \
      }                                                                       \
    }                                                                         \
    __syncthreads(); /* C: gates ready */                                     \
    unsigned long long pv0 = 0, pv1 = 0;                                      \
    if ((TP) < SEQ) {                                                         \
      unsigned* mf = ((O) ? flagB : flagA) + prodIdx * 16;                    \
      while (__hip_atomic_load(mf, __ATOMIC_RELAXED,                          \
                               __HIP_MEMORY_SCOPE_AGENT) < (unsigned)(TP))    \
        __builtin_amdgcn_s_sleep(1);                                          \
      const unsigned long long* hin = (const unsigned long long*)             \
          (hbuf + ((size_t)g * 4 + (O) * 2 + ((TP) & 1)) * 2048);             \
      pv0 = __hip_atomic_load(hin + tid, __ATOMIC_RELAXED,                    \
                              __HIP_MEMORY_SCOPE_AGENT);                      \
      pv1 = __hip_atomic_load(hin + 512 + tid, __ATOMIC_RELAXED,              \
                              __HIP_MEMORY_SCOPE_AGENT);                      \
    }                                                                         \
    float hval = 0.f;                                                         \
    if (tid < 256) {                                                          \
      float r_ = sigm(gate_s[0][sb][su] + b_r);                               \
      float z_ = sigm(gate_s[1][sb][su] + b_z);                               \
      float n_ = tanhf(xn_s[sb][su] + b_in +                                  \
                       r_ * (gate_s[2][sb][su] + b_hn));                      \
      hval = (1.0f - z_) * n_ + z_ * (HPREV);                                 \
      HPREV = hval;                                                           \
      ssum += hval; ssq += hval * hval;                                       \
      float hp = __shfl_xor(hval, 1);                                         \
      if ((tid & 1) == 0) {                                                   \
        uint32_t packed = (uint32_t)f2bf(hval) | ((uint32_t)f2bf(hp) << 16);  \
        uint32_t* hout =                                                      \
            hbuf + ((size_t)g * 4 + (H) * 2 + (((T) + 1) & 1)) * 2048;        \
        __hip_atomic_store(hout + ((sb * HD + u0 + su) >> 1), packed,         \
                           __ATOMIC_RELAXED, __HIP_MEMORY_SCOPE_AGENT);       \
      }                                                                       \
    }                                                                         \
    __syncthreads(); /* D: drains vmcnt -> h committed at LLC */              \
    if (tid == 0)                                                             \
      __hip_atomic_store(((H) ? flagB : flagA) + wg * 16,                     \
                         (unsigned)((T) + 1), __ATOMIC_RELAXED,               \
                         __HIP_MEMORY_SCOPE_AGENT);                           \
    if (tid < 256)                                                            \
      o1[((size_t)(bg + (H) * HB + sb) * SEQ + (T)) * HD + u0 + su] = hval;   \
    if ((TP) < SEQ) {                                                         \
      *(unsigned long long*)(&h_s[O][tid >> 7][(tid & 127) * 4]) = pv0;       \
      int q = 512 + tid;                                                      \
      *(unsigned long long*)(&h_s[O][q >> 7][(q & 127) * 4]) = pv1;           \
      if (lane < 40)                                                          \
        x_s[O][wave][lane] = f2bf(                                            \
            x[((size_t)(bg + (O) * HB + wave) * SEQ + (TP)) * DX + lane]);    \
    }                                                                         \
    __syncthreads(); /* B: h_s[O], x_s[O] ready */                            \
  } while (0)

  for (int t = 0; t < SEQ; ++t) {
    GRU_SUB(0, 1, t, t, hprevA);       // process A@t, prefetch B@t
    GRU_SUB(1, 0, t, t + 1, hprevB);   // process B@t, prefetch A@t+1
  }
#undef GRU_SUB

  if (tid < 256) {
    atomicAdd(&stats[u0 + su], ssum);
    atomicAdd(&stats[HD + u0 + su], ssq);
  }
}

// ---------------- LSTM persistent kernel ----------------
__global__ __launch_bounds__(512, 1) void lstm_kernel(
    const float* __restrict__ x, const float* __restrict__ Wih,
    const float* __restrict__ Whh, const float* __restrict__ bih,
    const float* __restrict__ bhh, const float* __restrict__ ssr,
    unsigned* __restrict__ flags, uint32_t* __restrict__ hbuf,
    float* __restrict__ o2)
{
  const int wg = blockIdx.x & (GW - 1);
  const int g  = blockIdx.x >> 4;
  const int tid = threadIdx.x;
  const int wave = tid >> 6;
  const int lane = tid & 63;
  const int u0 = wg * NU;
  const int bg = g * MB;

  __shared__ __align__(16) unsigned short h_s[2][HB][520];
  __shared__ __align__(16) unsigned short x_s[2][HB][72];  // 40 ssr, 41.. pad
  __shared__ float gate_s[4][HB][NU];

  short8 bfrag[18];
  const int myGate = wave >> 1;
  const int ut = wave & 1;
  const int kq = (lane >> 4) * 8;
  {
    const int row = myGate * HD + u0 + ut * 16 + (lane & 15);
    for (int kt = 0; kt < 16; ++kt) {
      const float* p = Whh + (size_t)row * HD + kt * 32 + kq;
      short8 f;
#pragma unroll
      for (int j = 0; j < 8; ++j) f[j] = (short)f2bf(p[j]);
      bfrag[kt] = f;
    }
    for (int kt = 16; kt < 18; ++kt) {     // Wih has 41 cols (x, ssr)
      short8 f;
#pragma unroll
      for (int j = 0; j < 8; ++j) {
        int c = kt * 32 + kq + j - HD;
        float v = (c < 41) ? Wih[(size_t)row * 41 + c] : 0.0f;
        f[j] = (short)f2bf(v);
      }
      bfrag[kt] = f;
    }
  }

  const int sb = tid >> 5;
  const int su = tid & 31;
  float cregA = 0.f, cregB = 0.f;
  const float b_i = bih[u0 + su] + bhh[u0 + su];
  const float b_f = bih[HD + u0 + su] + bhh[HD + u0 + su];
  const float b_g = bih[2 * HD + u0 + su] + bhh[2 * HD + u0 + su];
  const float b_o = bih[3 * HD + u0 + su] + bhh[3 * HD + u0 + su];

  unsigned* flagA = flags + (size_t)(g * 2 + 0) * GW * 16;
  unsigned* flagB = flags + (size_t)(g * 2 + 1) * GW * 16;
  const int prodIdx = (tid & 127) >> 3;

  if (tid < 288) ((unsigned long long*)x_s)[tid] = 0ull;
  __syncthreads();
  {
    *(unsigned long long*)(&h_s[0][tid >> 7][(tid & 127) * 4]) = 0ull;
    int q = 512 + tid;
    *(unsigned long long*)(&h_s[0][q >> 7][(q & 127) * 4]) = 0ull;
    if (lane < 40)
      x_s[0][wave][lane] = f2bf(x[((size_t)(bg + wave) * SEQ) * DX + lane]);
    else if (lane == 40)
      x_s[0][wave][40] = f2bf(ssr[(size_t)(bg + wave) * SEQ]);
  }
  __syncthreads();

#define LSTM_SUB(H, O, T, TP, CREG)                                           \
  do {                                                                        \
    {                                                                         \
      const int m = lane & 7;                                                 \
      f32x4 a0 = {0.f, 0.f, 0.f, 0.f}, a1 = {0.f, 0.f, 0.f, 0.f};             \
      _Pragma("unroll")                                                       \
      for (int kt = 0; kt < 16; kt += 2) {                                    \
        short8 ha0 = *(const short8*)(&h_s[H][m][kt * 32 + kq]);              \
        short8 ha1 = *(const short8*)(&h_s[H][m][(kt + 1) * 32 + kq]);        \
        a0 = MFMA_B16(ha0, bfrag[kt], a0);                                    \
        a1 = MFMA_B16(ha1, bfrag[kt + 1], a1);                                \
      }                                                                       \
      short8 ax0 = *(const short8*)(&x_s[H][m][kq]);                          \
      short8 ax1 = *(const short8*)(&x_s[H][m][32 + kq]);                     \
      a0 = MFMA_B16(ax0, bfrag[16], a0);                                      \
      a1 = MFMA_B16(ax1, bfrag[17], a1);                                      \
      f32x4 acc = a0 + a1;                                                    \
      if (lane < 32) {                                                        \
        _Pragma("unroll")                                                     \
        for (int r = 0; r < 4; ++r)                                           \
          gate_s[myGate][(lane >> 4) * 4 + r][ut * 16 + (lane & 15)] = acc[r];\
      }                                                                       \
    }                                                                         \
    __syncthreads(); /* C */                                                  \
    unsigned long long pv0 = 0, pv1 = 0;                                      \
    if ((TP) < SEQ) {                                                         \
      unsigned* mf = ((O) ? flagB : flagA) + prodIdx * 16;                    \
      while (__hip_atomic_load(mf, __ATOMIC_RELAXED,                          \
                               __HIP_MEMORY_SCOPE_AGENT) < (unsigned)(TP))    \
        __builtin_amdgcn_s_sleep(1);                                          \
      const unsigned long long* hin = (const unsigned long long*)             \
          (hbuf + ((size_t)g * 4 + (O) * 2 + ((TP) & 1)) * 2048);             \
      pv0 = __hip_atomic_load(hin + tid, __ATOMIC_RELAXED,                    \
                              __HIP_MEMORY_SCOPE_AGENT);                      \
      pv1 = __hip_atomic_load(hin + 512 + tid, __ATOMIC_RELAXED,              \
                              __HIP_MEMORY_SCOPE_AGENT);                      \
    }                                                                         \
    float hval = 0.f;                                                         \
    if (tid < 256) {                                                          \
      float gi  = sigm(gate_s[0][sb][su] + b_i);                              \
      float gf_ = sigm(gate_s[1][sb][su] + b_f);                              \
      float gg  = tanhf(gate_s[2][sb][su] + b_g);                             \
      float go  = sigm(gate_s[3][sb][su] + b_o);                              \
      CREG = gf_ * (CREG) + gi * gg;                                          \
      hval = go * tanhf(CREG);                                                \
      float hp = __shfl_xor(hval, 1);                                         \
      if ((tid & 1) == 0) {                                                   \
        uint32_t packed = (uint32_t)f2bf(hval) | ((uint32_t)f2bf(hp) << 16);  \
        uint32_t* hout =                                                      \
            hbuf + ((size_t)g * 4 + (H) * 2 + (((T) + 1) & 1)) * 2048;        \
        __hip_atomic_store(hout + ((sb * HD + u0 + su) >> 1), packed,         \
                           __ATOMIC_RELAXED, __HIP_MEMORY_SCOPE_AGENT);       \
      }                                                                       \
    }                                                                         \
    __syncthreads(); /* D */                                                  \
    if (tid == 0)                                                             \
      __hip_atomic_store(((H) ? flagB : flagA) + wg * 16,                     \
                         (unsigned)((T) + 1), __ATOMIC_RELAXED,               \
                         __HIP_MEMORY_SCOPE_AGENT);                           \
    if (tid < 256)                                                            \
      o2[((size_t)(bg + (H) * HB + sb) * SEQ + (T)) * HD + u0 + su] = hval;   \
    if ((TP) < SEQ) {                                                         \
      *(unsigned long long*)(&h_s[O][tid >> 7][(tid & 127) * 4]) = pv0;       \
      int q = 512 + tid;                                                      \
      *(unsigned long long*)(&h_s[O][q >> 7][(q & 127) * 4]) = pv1;           \
      if (lane < 40)                                                          \
        x_s[O][wave][lane] = f2bf(                                            \
            x[((size_t)(bg + (O) * HB + wave) * SEQ + (TP)) * DX + lane]);    \
      else if (lane == 40)                                                    \
        x_s[O][wave][40] =                                                    \
            f2bf(ssr[(size_t)(bg + (O) * HB + wave) * SEQ + (TP)]);           \
    }                                                                         \
    __syncthreads(); /* B */                                                  \
  } while (0)

  for (int t = 0; t < SEQ; ++t) {
    LSTM_SUB(0, 1, t, t, cregA);
    LSTM_SUB(1, 0, t, t + 1, cregB);
  }
#undef LSTM_SUB
}

// ---------------- BN-coefficient kernel (1 block) ----------------
__global__ __launch_bounds__(512) void coef_kernel(
    const float* __restrict__ stats, const float* __restrict__ fc1_w,
    const float* __restrict__ fc1_b, const float* __restrict__ fc2_w,
    const float* __restrict__ fc2_b, const float* __restrict__ gamma,
    const float* __restrict__ beta, float* __restrict__ coef)
{
  __shared__ float r1[512], r2[512];
  const int j = threadIdx.x;
  const float inv_n = 1.0f / 32768.0f;
  float mean = stats[j] * inv_n;
  float var = stats[HD + j] * inv_n - mean * mean;
  float scale = gamma[j] * rsqrtf(var + 1e-5f);
  float shift = beta[j] - mean * scale;
  coef[j] = fc1_w[j] * scale;
  coef[HD + j] = fc2_w[j] * scale;
  r1[j] = fc1_w[j] * shift;
  r2[j] = fc2_w[j] * shift;
  __syncthreads();
  for (int s = 256; s > 0; s >>= 1) {
    if (j < s) { r1[j] += r1[j + s]; r2[j] += r2[j + s]; }
    __syncthreads();
  }
  if (j == 0) {
    coef[2 * HD] = r1[0] + fc1_b[0];
    coef[2 * HD + 1] = r2[0] + fc2_b[0];
  }
}

// ---------------- ssr kernel: one wave per (b,t) row ----------------
__global__ __launch_bounds__(256) void ssr_kernel(
    const float* __restrict__ o1, const float* __restrict__ coef,
    float* __restrict__ ssr_ws, float* __restrict__ dssr)
{
  const int row = blockIdx.x * 4 + (threadIdx.x >> 6);
  const int lane = threadIdx.x & 63;
  const float* p = o1 + (size_t)row * HD + lane * 8;
  float s1 = 0.f, s2 = 0.f;
#pragma unroll
  for (int j = 0; j < 8; ++j) {
    float v = p[j];
    s1 += v * coef[lane * 8 + j];
    s2 += v * coef[HD + lane * 8 + j];
  }
#pragma unroll
  for (int off = 32; off > 0; off >>= 1) {
    s1 += __shfl_down(s1, off);
    s2 += __shfl_down(s2, off);
  }
  if (lane == 0) {
    float sr = fmaxf(s1 + coef[2 * HD], 0.0f);
    float w = fabsf(sigm(s2 + coef[2 * HD + 1]));
    float v = sr * (1.0f + w);
    ssr_ws[row] = v;
    dssr[row] = v;
  }
}

// ---------------- fc3 output kernel ----------------
__global__ __launch_bounds__(256) void out_kernel(
    const float* __restrict__ o2, const float* __restrict__ fc3_w,
    const float* __restrict__ fc3_b, float* __restrict__ dout)
{
  const int row = blockIdx.x * 4 + (threadIdx.x >> 6);
  const int lane = threadIdx.x & 63;
  const float* p = o2 + (size_t)row * HD + lane * 8;
  float s = 0.f;
#pragma unroll
  for (int j = 0; j < 8; ++j) s += p[j] * fc3_w[lane * 8 + j];
#pragma unroll
  for (int off = 32; off > 0; off >>= 1) s += __shfl_down(s, off);
  if (lane == 0) dout[row] = fmaxf(s + fc3_b[0], 0.0f);
}

extern "C" void kernel_launch(void* const* d_in, const int* in_sizes, int n_in,
                              void* d_out, int out_size, void* d_ws, size_t ws_size,
                              hipStream_t stream) {
  (void)in_sizes; (void)n_in; (void)out_size; (void)ws_size;
  const float* x    = (const float*)d_in[0];
  const float* gWih = (const float*)d_in[1];
  const float* gWhh = (const float*)d_in[2];
  const float* gbih = (const float*)d_in[3];
  const float* gbhh = (const float*)d_in[4];
  const float* lWih = (const float*)d_in[5];
  const float* lWhh = (const float*)d_in[6];
  const float* lbih = (const float*)d_in[7];
  const float* lbhh = (const float*)d_in[8];
  const float* fc1w = (const float*)d_in[9];
  const float* fc1b = (const float*)d_in[10];
  const float* fc2w = (const float*)d_in[11];
  const float* fc2b = (const float*)d_in[12];
  const float* fc3w = (const float*)d_in[13];
  const float* fc3b = (const float*)d_in[14];
  const float* gam  = (const float*)d_in[15];
  const float* bet  = (const float*)d_in[16];
  float* out = (float*)d_out;

  char* ws = (char*)d_ws;
  unsigned* flags_g = (unsigned*)(ws + 0);            // 4g x 2half x 16wg x 64B
  unsigned* flags_l = (unsigned*)(ws + 8192);
  float* stats      = (float*)(ws + 16384);           // 1024 f32
  float* coef       = (float*)(ws + 24576);           // 1026 f32
  float* ssr_ws     = (float*)(ws + 32768);           // 32768 f32
  uint32_t* hbuf_g  = (uint32_t*)(ws + 262144);       // 4g x 2half x 2par x 8KB
  uint32_t* hbuf_l  = (uint32_t*)(ws + 393216);       // 128KB
  float* o1 = (float*)(ws + 1048576);                 // 64MB
  float* o2 = o1 + (size_t)64 * SEQ * HD;             // 64MB

  hipMemsetAsync(ws, 0, 20480, stream);               // flags + stats
  hipMemsetAsync(ws + 262144, 0, 262144, stream);     // h exchange (h0=0)

  gru_kernel<<<dim3(64), dim3(512), 0, stream>>>(x, gWih, gWhh, gbih, gbhh,
                                                 flags_g, hbuf_g, o1, stats);
  coef_kernel<<<dim3(1), dim3(512), 0, stream>>>(stats, fc1w, fc1b, fc2w, fc2b,
                                                 gam, bet, coef);
  ssr_kernel<<<dim3(8192), dim3(256), 0, stream>>>(o1, coef, ssr_ws, out + 32768);
  lstm_kernel<<<dim3(64), dim3(512), 0, stream>>>(x, lWih, lWhh, lbih, lbhh, ssr_ws,
                                                  flags_l, hbuf_l, o2);
  out_kernel<<<dim3(8192), dim3(256), 0, stream>>>(o2, fc3w, fc3b, out);
}

// Round 5
// 3542.098 us; speedup vs baseline: 1.1845x; 1.1845x over previous
//
#include <hip/hip_runtime.h>
#include <stdint.h>

#define GW 16   // workgroups per group
#define NU 32   // hidden units per WG
#define HD 512
#define SEQ 512
#define DX 40
#define MB 16   // batch rows per group

using short8 = __attribute__((ext_vector_type(8))) short;
using f32x4  = __attribute__((ext_vector_type(4))) float;
typedef unsigned long long u64;

__device__ __forceinline__ unsigned short f2bf(float f) {
  uint32_t u = __builtin_bit_cast(uint32_t, f);
  u += 0x7fffu + ((u >> 16) & 1u);
  return (unsigned short)(u >> 16);
}
__device__ __forceinline__ float sigm(float x) { return 1.0f / (1.0f + __expf(-x)); }

#define MFMA_B16(a, b, c) __builtin_amdgcn_mfma_f32_16x16x32_bf16((a), (b), (c), 0, 0, 0)

// R8 = R7 + prologue race fix (__syncthreads between LDS zero-fill and x(0)
// staging — R7's zero-fill by slow waves could clobber fast waves' staging).
// Producer-consumer wave specialization. 640-thread blocks:
//   waves 0-7 COMPUTE (MFMA gates + elementwise; LDS only, no vmcnt waits)
//   waves 8-9 COMM    (publish h -> drain -> flag -> poll -> load -> stage)
// NO __syncthreads in the main loop; coordination via monotone LDS counters:
//   sync_s[0] cnt_gates: +1 per compute wave per step (gate/xn tiles in LDS)
//   sync_s[1] cnt_h:     +1 per elementwise wave (0-3) per step (h_stage ready)
//   sync_s[2] in_ready:  +1 per comm wave per iter (h_s/x_s staged for t+1)
//   sync_s[3] cnt_pub:   +1 per comm wave per iter (its global h stores drained)
// Remote exchange: R3 protocol (bf16x2 words, relaxed AGENT atomics; per-WG
// flag stored only after both comm waves' vmcnt(0) drains, via cnt_pub).
// Overwrite safety ledger (hand-verified, no barriers):
//   gate_s/xn_s@t+1 vs elementwise reads@t:  MFMA(t+1) <- in_ready>=2(t+1)
//     <- comm iter t <- cnt_h>=4(t+1) <- elementwise t done.
//   h_s/x_s parity overwrite @comm iter u vs MFMA reads @step u-1:
//     comm u <- cnt_h>=4(u+1) <- elementwise u <- cnt_gates>=8(u+1) <- MFMA u.
//   h_stage overwrite @elementwise t+1 vs comm read @iter t:
//     elementwise t+1 <- MFMA t+1 <- in_ready>=2(t+1) <- comm iter t done.
//   remote hbuf overwrite: 2-deep flag induction as in R0/R3 (flag[C]>=u
//     observed at iter u-1 implies C's iter u-2 reads done; writer's iter u
//     write follows its own iter u-1 wave-join over all 16 flags).

// ---------------- GRU persistent kernel ----------------
__global__ __launch_bounds__(640, 1) void gru_kernel(
    const float* __restrict__ x, const float* __restrict__ Wih,
    const float* __restrict__ Whh, const float* __restrict__ bih,
    const float* __restrict__ bhh, unsigned* __restrict__ flags,
    u64* __restrict__ hbuf, float* __restrict__ o1, float* __restrict__ stats)
{
  const int wg = blockIdx.x & (GW - 1);
  const int g  = blockIdx.x >> 4;
  const int tid = threadIdx.x;
  const int wave = tid >> 6;
  const int lane = tid & 63;
  const int u0 = wg * NU;
  const int bg = g * MB;

  __shared__ __align__(16) unsigned short h_s[2][MB][520];
  __shared__ __align__(16) unsigned short x_s[2][MB][72];  // 40..63 zero pad
  __shared__ float gate_s[3][MB][NU];
  __shared__ float xn_s[MB][NU];
  __shared__ uint32_t h_stage[256];   // bf16x2 words, [row*16 + su/2]
  __shared__ uint32_t sync_s[4];

  // weight B-fragments. B[k][n]: n=lane&15, k=(lane>>4)*8+j.
  short8 bfrag[18];
  const int myGate = wave >> 1;
  const int ut = wave & 1;
  const int kq = (lane >> 4) * 8;
  if (wave < 6) {
    const int row = myGate * HD + u0 + ut * 16 + (lane & 15);
    for (int kt = 0; kt < 16; ++kt) {
      const float* p = Whh + (size_t)row * HD + kt * 32 + kq;
      short8 f;
#pragma unroll
      for (int j = 0; j < 8; ++j) f[j] = (short)f2bf(p[j]);
      bfrag[kt] = f;
    }
    for (int kt = 16; kt < 18; ++kt) {     // x cols: r,z only (n via xn MFMA)
      short8 f;
#pragma unroll
      for (int j = 0; j < 8; ++j) {
        int c = kt * 32 + kq + j - HD;
        float v = (myGate < 2 && c < DX) ? Wih[(size_t)row * DX + c] : 0.0f;
        f[j] = (short)f2bf(v);
      }
      bfrag[kt] = f;
    }
  } else if (wave < 8) {                   // waves 6,7: Wn fragments, K=64 pad
    const int row = 2 * HD + u0 + (wave - 6) * 16 + (lane & 15);
    for (int kt = 0; kt < 2; ++kt) {
      short8 f;
#pragma unroll
      for (int j = 0; j < 8; ++j) {
        int c = kt * 32 + kq + j;
        f[j] = (short)((c < DX) ? f2bf(Wih[(size_t)row * DX + c]) : 0);
      }
      bfrag[kt] = f;
    }
  }

  const int sb = tid >> 5;   // row 0..7 (elementwise, tid<256; also row sb+8)
  const int su = tid & 31;
  float b_r = 0.f, b_z = 0.f, b_in = 0.f, b_hn = 0.f;
  if (tid < 256) {
    b_r  = bih[u0 + su] + bhh[u0 + su];
    b_z  = bih[HD + u0 + su] + bhh[HD + u0 + su];
    b_in = bih[2 * HD + u0 + su];
    b_hn = bhh[2 * HD + u0 + su];
  }

  // prologue: zero h_s (h0=0) and x_s; BARRIER; then stage x(0).
  for (int i = tid; i < 4160; i += 640) ((u64*)h_s)[i] = 0ull;
  for (int i = tid; i < 576;  i += 640) ((u64*)x_s)[i] = 0ull;
  if (tid < 4) sync_s[tid] = 0;
  __syncthreads();   // zero-fill complete before staging (R7 race fix)
  {
    int r = tid / 40, c = tid % 40;   // 640 threads == 16*40 exactly
    x_s[0][r][c] = f2bf(x[((size_t)(bg + r) * SEQ) * DX + c]);
  }
  __syncthreads();

  unsigned* gf = flags + g * GW * 16;     // 64B-strided per-WG flags

  if (wave < 8) {
    // ================= COMPUTE =================
    float hpA = 0.f, hpB = 0.f, ssum = 0.f, ssq = 0.f;
    for (int t = 0; t < SEQ; ++t) {
      if (t) {
        while (__hip_atomic_load(&sync_s[2], __ATOMIC_ACQUIRE,
                                 __HIP_MEMORY_SCOPE_WORKGROUP) < 2u * (unsigned)t)
          __builtin_amdgcn_s_sleep(1);
      }
      const int p = t & 1;
      if (wave < 6) {
        const int m = lane & 15;
        f32x4 a0 = {0.f, 0.f, 0.f, 0.f}, a1 = {0.f, 0.f, 0.f, 0.f};
#pragma unroll
        for (int kt = 0; kt < 16; kt += 2) {
          short8 ha0 = *(const short8*)(&h_s[p][m][kt * 32 + kq]);
          short8 ha1 = *(const short8*)(&h_s[p][m][(kt + 1) * 32 + kq]);
          a0 = MFMA_B16(ha0, bfrag[kt], a0);
          a1 = MFMA_B16(ha1, bfrag[kt + 1], a1);
        }
        short8 ax0 = *(const short8*)(&x_s[p][m][kq]);
        short8 ax1 = *(const short8*)(&x_s[p][m][32 + kq]);
        a0 = MFMA_B16(ax0, bfrag[16], a0);
        a1 = MFMA_B16(ax1, bfrag[17], a1);
        f32x4 acc = a0 + a1;
#pragma unroll
        for (int r = 0; r < 4; ++r)   // C/D: col=lane&15, row=(lane>>4)*4+r
          gate_s[myGate][(lane >> 4) * 4 + r][ut * 16 + (lane & 15)] = acc[r];
      } else {
        const int m = lane & 15;
        f32x4 acc = {0.f, 0.f, 0.f, 0.f};
        short8 ax0 = *(const short8*)(&x_s[p][m][kq]);
        short8 ax1 = *(const short8*)(&x_s[p][m][32 + kq]);
        acc = MFMA_B16(ax0, bfrag[0], acc);
        acc = MFMA_B16(ax1, bfrag[1], acc);
#pragma unroll
        for (int r = 0; r < 4; ++r)
          xn_s[(lane >> 4) * 4 + r][(wave - 6) * 16 + (lane & 15)] = acc[r];
      }
      asm volatile("s_waitcnt lgkmcnt(0)" ::: "memory");
      if (lane == 0)
        __hip_atomic_fetch_add(&sync_s[0], 1u, __ATOMIC_RELAXED,
                               __HIP_MEMORY_SCOPE_WORKGROUP);
      if (tid < 256) {
        while (__hip_atomic_load(&sync_s[0], __ATOMIC_ACQUIRE,
                                 __HIP_MEMORY_SCOPE_WORKGROUP) < 8u * (unsigned)(t + 1))
          __builtin_amdgcn_s_sleep(1);
        float rA = sigm(gate_s[0][sb][su] + b_r);
        float zA = sigm(gate_s[1][sb][su] + b_z);
        float nA = tanhf(xn_s[sb][su] + b_in + rA * (gate_s[2][sb][su] + b_hn));
        float hA = (1.0f - zA) * nA + zA * hpA;
        float rB = sigm(gate_s[0][sb + 8][su] + b_r);
        float zB = sigm(gate_s[1][sb + 8][su] + b_z);
        float nB = tanhf(xn_s[sb + 8][su] + b_in + rB * (gate_s[2][sb + 8][su] + b_hn));
        float hB = (1.0f - zB) * nB + zB * hpB;
        hpA = hA; hpB = hB;
        ssum += hA + hB; ssq += hA * hA + hB * hB;
        o1[((size_t)(bg + sb) * SEQ + t) * HD + u0 + su] = hA;       // fire&forget
        o1[((size_t)(bg + sb + 8) * SEQ + t) * HD + u0 + su] = hB;
        float pA = __shfl_xor(hA, 1);
        float pB = __shfl_xor(hB, 1);
        if ((su & 1) == 0) {
          h_stage[sb * 16 + (su >> 1)] =
              (uint32_t)f2bf(hA) | ((uint32_t)f2bf(pA) << 16);
          h_stage[(sb + 8) * 16 + (su >> 1)] =
              (uint32_t)f2bf(hB) | ((uint32_t)f2bf(pB) << 16);
        }
        asm volatile("s_waitcnt lgkmcnt(0)" ::: "memory");
        if (lane == 0)
          __hip_atomic_fetch_add(&sync_s[1], 1u, __ATOMIC_RELAXED,
                                 __HIP_MEMORY_SCOPE_WORKGROUP);
      }
    }
    if (tid < 256) {
      atomicAdd(&stats[u0 + su], ssum);
      atomicAdd(&stats[HD + u0 + su], ssq);
    }
  } else {
    // ================= COMM =================
    const int ct = tid - 512;             // 0..127
    const int prow = ct >> 3;             // publish row / producer index
    const int pquad = ct & 7;
    unsigned* myFlag = gf + prow * 16;
    for (int u = 0; u < SEQ - 1; ++u) {
      // (a) wait elementwise(u) -> h(u+1) in h_stage
      while (__hip_atomic_load(&sync_s[1], __ATOMIC_ACQUIRE,
                               __HIP_MEMORY_SCOPE_WORKGROUP) < 4u * (unsigned)(u + 1))
        __builtin_amdgcn_s_sleep(1);
      // (b) pack from h_stage
      uint32_t w0 = h_stage[prow * 16 + pquad * 2];
      uint32_t w1 = h_stage[prow * 16 + pquad * 2 + 1];
      u64 pub = ((u64)w1 << 32) | (u64)w0;
      // (c) publish + drain (this wave only), then joint flag via cnt_pub
      u64* hb = hbuf + ((size_t)g * 2 + ((u + 1) & 1)) * 2048;
      __hip_atomic_store(hb + prow * 128 + wg * 8 + pquad, pub,
                         __ATOMIC_RELAXED, __HIP_MEMORY_SCOPE_AGENT);
      asm volatile("s_waitcnt vmcnt(0)" ::: "memory");
      if (lane == 0)
        __hip_atomic_fetch_add(&sync_s[3], 1u, __ATOMIC_RELAXED,
                               __HIP_MEMORY_SCOPE_WORKGROUP);
      if (wave == 8) {
        while (__hip_atomic_load(&sync_s[3], __ATOMIC_ACQUIRE,
                                 __HIP_MEMORY_SCOPE_WORKGROUP) < 2u * (unsigned)(u + 1))
          __builtin_amdgcn_s_sleep(1);
        if (lane == 0)
          __hip_atomic_store(gf + wg * 16, (unsigned)(u + 1),
                             __ATOMIC_RELAXED, __HIP_MEMORY_SCOPE_AGENT);
      }
      // (c2) x(u+1) prefetch into regs (latency rides under poll)
      float xv[5];
      const int xi = ct * 5;
#pragma unroll
      for (int i = 0; i < 5; ++i) {
        int idx = xi + i, r = idx / 40, c = idx % 40;
        xv[i] = x[((size_t)(bg + r) * SEQ + (u + 1)) * DX + c];
      }
      // (d) poll my producer's flag
      while (__hip_atomic_load(myFlag, __ATOMIC_RELAXED,
                               __HIP_MEMORY_SCOPE_AGENT) < (unsigned)(u + 1))
        __builtin_amdgcn_s_sleep(1);
      // (e) load h(u+1) tile (16 x u64, one producer per thread)
      u64 hv[16];
#pragma unroll
      for (int i = 0; i < 16; ++i)
        hv[i] = __hip_atomic_load(hb + i * 128 + ct, __ATOMIC_RELAXED,
                                  __HIP_MEMORY_SCOPE_AGENT);
      // (f) stage h_s/x_s for step u+1
      const int np = (u + 1) & 1;
#pragma unroll
      for (int i = 0; i < 16; ++i)
        *(u64*)(&h_s[np][i][ct * 4]) = hv[i];
#pragma unroll
      for (int i = 0; i < 5; ++i) {
        int idx = xi + i, r = idx / 40, c = idx % 40;
        x_s[np][r][c] = f2bf(xv[i]);
      }
      asm volatile("s_waitcnt lgkmcnt(0)" ::: "memory");
      if (lane == 0)
        __hip_atomic_fetch_add(&sync_s[2], 1u, __ATOMIC_RELAXED,
                               __HIP_MEMORY_SCOPE_WORKGROUP);
    }
  }
}

// ---------------- LSTM persistent kernel ----------------
__global__ __launch_bounds__(640, 1) void lstm_kernel(
    const float* __restrict__ x, const float* __restrict__ Wih,
    const float* __restrict__ Whh, const float* __restrict__ bih,
    const float* __restrict__ bhh, const float* __restrict__ ssr,
    unsigned* __restrict__ flags, u64* __restrict__ hbuf,
    float* __restrict__ o2)
{
  const int wg = blockIdx.x & (GW - 1);
  const int g  = blockIdx.x >> 4;
  const int tid = threadIdx.x;
  const int wave = tid >> 6;
  const int lane = tid & 63;
  const int u0 = wg * NU;
  const int bg = g * MB;

  __shared__ __align__(16) unsigned short h_s[2][MB][520];
  __shared__ __align__(16) unsigned short x_s[2][MB][72];  // 40 ssr, 41.. pad
  __shared__ float gate_s[4][MB][NU];
  __shared__ uint32_t h_stage[256];
  __shared__ uint32_t sync_s[4];

  short8 bfrag[18];
  const int myGate = wave >> 1;            // 0..3 for waves 0..7
  const int ut = wave & 1;
  const int kq = (lane >> 4) * 8;
  if (wave < 8) {
    const int row = myGate * HD + u0 + ut * 16 + (lane & 15);
    for (int kt = 0; kt < 16; ++kt) {
      const float* p = Whh + (size_t)row * HD + kt * 32 + kq;
      short8 f;
#pragma unroll
      for (int j = 0; j < 8; ++j) f[j] = (short)f2bf(p[j]);
      bfrag[kt] = f;
    }
    for (int kt = 16; kt < 18; ++kt) {     // Wih has 41 cols (x, ssr)
      short8 f;
#pragma unroll
      for (int j = 0; j < 8; ++j) {
        int c = kt * 32 + kq + j - HD;
        float v = (c < 41) ? Wih[(size_t)row * 41 + c] : 0.0f;
        f[j] = (short)f2bf(v);
      }
      bfrag[kt] = f;
    }
  }

  const int sb = tid >> 5;
  const int su = tid & 31;
  float b_i = 0.f, b_f = 0.f, b_g = 0.f, b_o = 0.f;
  if (tid < 256) {
    b_i = bih[u0 + su] + bhh[u0 + su];
    b_f = bih[HD + u0 + su] + bhh[HD + u0 + su];
    b_g = bih[2 * HD + u0 + su] + bhh[2 * HD + u0 + su];
    b_o = bih[3 * HD + u0 + su] + bhh[3 * HD + u0 + su];
  }

  for (int i = tid; i < 4160; i += 640) ((u64*)h_s)[i] = 0ull;
  for (int i = tid; i < 576;  i += 640) ((u64*)x_s)[i] = 0ull;
  if (tid < 4) sync_s[tid] = 0;
  __syncthreads();   // zero-fill complete before staging (R7 race fix)
  {
    int r = tid / 40, c = tid % 40;
    x_s[0][r][c] = f2bf(x[((size_t)(bg + r) * SEQ) * DX + c]);
  }
  if (tid < 16) x_s[0][tid][40] = f2bf(ssr[(size_t)(bg + tid) * SEQ]);
  __syncthreads();

  unsigned* gf = flags + g * GW * 16;

  if (wave < 8) {
    // ================= COMPUTE =================
    float cA = 0.f, cB = 0.f;
    for (int t = 0; t < SEQ; ++t) {
      if (t) {
        while (__hip_atomic_load(&sync_s[2], __ATOMIC_ACQUIRE,
                                 __HIP_MEMORY_SCOPE_WORKGROUP) < 2u * (unsigned)t)
          __builtin_amdgcn_s_sleep(1);
      }
      const int p = t & 1;
      {
        const int m = lane & 15;
        f32x4 a0 = {0.f, 0.f, 0.f, 0.f}, a1 = {0.f, 0.f, 0.f, 0.f};
#pragma unroll
        for (int kt = 0; kt < 16; kt += 2) {
          short8 ha0 = *(const short8*)(&h_s[p][m][kt * 32 + kq]);
          short8 ha1 = *(const short8*)(&h_s[p][m][(kt + 1) * 32 + kq]);
          a0 = MFMA_B16(ha0, bfrag[kt], a0);
          a1 = MFMA_B16(ha1, bfrag[kt + 1], a1);
        }
        short8 ax0 = *(const short8*)(&x_s[p][m][kq]);
        short8 ax1 = *(const short8*)(&x_s[p][m][32 + kq]);
        a0 = MFMA_B16(ax0, bfrag[16], a0);
        a1 = MFMA_B16(ax1, bfrag[17], a1);
        f32x4 acc = a0 + a1;
#pragma unroll
        for (int r = 0; r < 4; ++r)
          gate_s[myGate][(lane >> 4) * 4 + r][ut * 16 + (lane & 15)] = acc[r];
      }
      asm volatile("s_waitcnt lgkmcnt(0)" ::: "memory");
      if (lane == 0)
        __hip_atomic_fetch_add(&sync_s[0], 1u, __ATOMIC_RELAXED,
                               __HIP_MEMORY_SCOPE_WORKGROUP);
      if (tid < 256) {
        while (__hip_atomic_load(&sync_s[0], __ATOMIC_ACQUIRE,
                                 __HIP_MEMORY_SCOPE_WORKGROUP) < 8u * (unsigned)(t + 1))
          __builtin_amdgcn_s_sleep(1);
        float giA = sigm(gate_s[0][sb][su] + b_i);
        float gfA = sigm(gate_s[1][sb][su] + b_f);
        float ggA = tanhf(gate_s[2][sb][su] + b_g);
        float goA = sigm(gate_s[3][sb][su] + b_o);
        cA = gfA * cA + giA * ggA;
        float hA = goA * tanhf(cA);
        float giB = sigm(gate_s[0][sb + 8][su] + b_i);
        float gfB = sigm(gate_s[1][sb + 8][su] + b_f);
        float ggB = tanhf(gate_s[2][sb + 8][su] + b_g);
        float goB = sigm(gate_s[3][sb + 8][su] + b_o);
        cB = gfB * cB + giB * ggB;
        float hB = goB * tanhf(cB);
        o2[((size_t)(bg + sb) * SEQ + t) * HD + u0 + su] = hA;
        o2[((size_t)(bg + sb + 8) * SEQ + t) * HD + u0 + su] = hB;
        float pA = __shfl_xor(hA, 1);
        float pB = __shfl_xor(hB, 1);
        if ((su & 1) == 0) {
          h_stage[sb * 16 + (su >> 1)] =
              (uint32_t)f2bf(hA) | ((uint32_t)f2bf(pA) << 16);
          h_stage[(sb + 8) * 16 + (su >> 1)] =
              (uint32_t)f2bf(hB) | ((uint32_t)f2bf(pB) << 16);
        }
        asm volatile("s_waitcnt lgkmcnt(0)" ::: "memory");
        if (lane == 0)
          __hip_atomic_fetch_add(&sync_s[1], 1u, __ATOMIC_RELAXED,
                                 __HIP_MEMORY_SCOPE_WORKGROUP);
      }
    }
  } else {
    // ================= COMM =================
    const int ct = tid - 512;
    const int prow = ct >> 3;
    const int pquad = ct & 7;
    unsigned* myFlag = gf + prow * 16;
    for (int u = 0; u < SEQ - 1; ++u) {
      while (__hip_atomic_load(&sync_s[1], __ATOMIC_ACQUIRE,
                               __HIP_MEMORY_SCOPE_WORKGROUP) < 4u * (unsigned)(u + 1))
        __builtin_amdgcn_s_sleep(1);
      uint32_t w0 = h_stage[prow * 16 + pquad * 2];
      uint32_t w1 = h_stage[prow * 16 + pquad * 2 + 1];
      u64 pub = ((u64)w1 << 32) | (u64)w0;
      u64* hb = hbuf + ((size_t)g * 2 + ((u + 1) & 1)) * 2048;
      __hip_atomic_store(hb + prow * 128 + wg * 8 + pquad, pub,
                         __ATOMIC_RELAXED, __HIP_MEMORY_SCOPE_AGENT);
      asm volatile("s_waitcnt vmcnt(0)" ::: "memory");
      if (lane == 0)
        __hip_atomic_fetch_add(&sync_s[3], 1u, __ATOMIC_RELAXED,
                               __HIP_MEMORY_SCOPE_WORKGROUP);
      if (wave == 8) {
        while (__hip_atomic_load(&sync_s[3], __ATOMIC_ACQUIRE,
                                 __HIP_MEMORY_SCOPE_WORKGROUP) < 2u * (unsigned)(u + 1))
          __builtin_amdgcn_s_sleep(1);
        if (lane == 0)
          __hip_atomic_store(gf + wg * 16, (unsigned)(u + 1),
                             __ATOMIC_RELAXED, __HIP_MEMORY_SCOPE_AGENT);
      }
      float xv[5];
      const int xi = ct * 5;
#pragma unroll
      for (int i = 0; i < 5; ++i) {
        int idx = xi + i, r = idx / 40, c = idx % 40;
        xv[i] = x[((size_t)(bg + r) * SEQ + (u + 1)) * DX + c];
      }
      float sv = 0.f;
      if (ct < 16) sv = ssr[(size_t)(bg + ct) * SEQ + (u + 1)];
      while (__hip_atomic_load(myFlag, __ATOMIC_RELAXED,
                               __HIP_MEMORY_SCOPE_AGENT) < (unsigned)(u + 1))
        __builtin_amdgcn_s_sleep(1);
      u64 hv[16];
#pragma unroll
      for (int i = 0; i < 16; ++i)
        hv[i] = __hip_atomic_load(hb + i * 128 + ct, __ATOMIC_RELAXED,
                                  __HIP_MEMORY_SCOPE_AGENT);
      const int np = (u + 1) & 1;
#pragma unroll
      for (int i = 0; i < 16; ++i)
        *(u64*)(&h_s[np][i][ct * 4]) = hv[i];
#pragma unroll
      for (int i = 0; i < 5; ++i) {
        int idx = xi + i, r = idx / 40, c = idx % 40;
        x_s[np][r][c] = f2bf(xv[i]);
      }
      if (ct < 16) x_s[np][ct][40] = f2bf(sv);
      asm volatile("s_waitcnt lgkmcnt(0)" ::: "memory");
      if (lane == 0)
        __hip_atomic_fetch_add(&sync_s[2], 1u, __ATOMIC_RELAXED,
                               __HIP_MEMORY_SCOPE_WORKGROUP);
    }
  }
}

// ---------------- BN-coefficient kernel (1 block) ----------------
__global__ __launch_bounds__(512) void coef_kernel(
    const float* __restrict__ stats, const float* __restrict__ fc1_w,
    const float* __restrict__ fc1_b, const float* __restrict__ fc2_w,
    const float* __restrict__ fc2_b, const float* __restrict__ gamma,
    const float* __restrict__ beta, float* __restrict__ coef)
{
  __shared__ float r1[512], r2[512];
  const int j = threadIdx.x;
  const float inv_n = 1.0f / 32768.0f;
  float mean = stats[j] * inv_n;
  float var = stats[HD + j] * inv_n - mean * mean;
  float scale = gamma[j] * rsqrtf(var + 1e-5f);
  float shift = beta[j] - mean * scale;
  coef[j] = fc1_w[j] * scale;
  coef[HD + j] = fc2_w[j] * scale;
  r1[j] = fc1_w[j] * shift;
  r2[j] = fc2_w[j] * shift;
  __syncthreads();
  for (int s = 256; s > 0; s >>= 1) {
    if (j < s) { r1[j] += r1[j + s]; r2[j] += r2[j + s]; }
    __syncthreads();
  }
  if (j == 0) {
    coef[2 * HD] = r1[0] + fc1_b[0];
    coef[2 * HD + 1] = r2[0] + fc2_b[0];
  }
}

// ---------------- ssr kernel: one wave per (b,t) row ----------------
__global__ __launch_bounds__(256) void ssr_kernel(
    const float* __restrict__ o1, const float* __restrict__ coef,
    float* __restrict__ ssr_ws, float* __restrict__ dssr)
{
  const int row = blockIdx.x * 4 + (threadIdx.x >> 6);
  const int lane = threadIdx.x & 63;
  const float* p = o1 + (size_t)row * HD + lane * 8;
  float s1 = 0.f, s2 = 0.f;
#pragma unroll
  for (int j = 0; j < 8; ++j) {
    float v = p[j];
    s1 += v * coef[lane * 8 + j];
    s2 += v * coef[HD + lane * 8 + j];
  }
#pragma unroll
  for (int off = 32; off > 0; off >>= 1) {
    s1 += __shfl_down(s1, off);
    s2 += __shfl_down(s2, off);
  }
  if (lane == 0) {
    float sr = fmaxf(s1 + coef[2 * HD], 0.0f);
    float w = fabsf(sigm(s2 + coef[2 * HD + 1]));
    float v = sr * (1.0f + w);
    ssr_ws[row] = v;
    dssr[row] = v;
  }
}

// ---------------- fc3 output kernel ----------------
__global__ __launch_bounds__(256) void out_kernel(
    const float* __restrict__ o2, const float* __restrict__ fc3_w,
    const float* __restrict__ fc3_b, float* __restrict__ dout)
{
  const int row = blockIdx.x * 4 + (threadIdx.x >> 6);
  const int lane = threadIdx.x & 63;
  const float* p = o2 + (size_t)row * HD + lane * 8;
  float s = 0.f;
#pragma unroll
  for (int j = 0; j < 8; ++j) s += p[j] * fc3_w[lane * 8 + j];
#pragma unroll
  for (int off = 32; off > 0; off >>= 1) s += __shfl_down(s, off);
  if (lane == 0) dout[row] = fmaxf(s + fc3_b[0], 0.0f);
}

extern "C" void kernel_launch(void* const* d_in, const int* in_sizes, int n_in,
                              void* d_out, int out_size, void* d_ws, size_t ws_size,
                              hipStream_t stream) {
  (void)in_sizes; (void)n_in; (void)out_size; (void)ws_size;
  const float* x    = (const float*)d_in[0];
  const float* gWih = (const float*)d_in[1];
  const float* gWhh = (const float*)d_in[2];
  const float* gbih = (const float*)d_in[3];
  const float* gbhh = (const float*)d_in[4];
  const float* lWih = (const float*)d_in[5];
  const float* lWhh = (const float*)d_in[6];
  const float* lbih = (const float*)d_in[7];
  const float* lbhh = (const float*)d_in[8];
  const float* fc1w = (const float*)d_in[9];
  const float* fc1b = (const float*)d_in[10];
  const float* fc2w = (const float*)d_in[11];
  const float* fc2b = (const float*)d_in[12];
  const float* fc3w = (const float*)d_in[13];
  const float* fc3b = (const float*)d_in[14];
  const float* gam  = (const float*)d_in[15];
  const float* bet  = (const float*)d_in[16];
  float* out = (float*)d_out;

  char* ws = (char*)d_ws;
  unsigned* flags_g = (unsigned*)(ws + 0);            // 4 groups x 16 WG x 64B
  unsigned* flags_l = (unsigned*)(ws + 4096);
  float* stats      = (float*)(ws + 16384);           // 1024 f32
  float* coef       = (float*)(ws + 24576);           // 1026 f32
  float* ssr_ws     = (float*)(ws + 32768);           // 32768 f32
  u64* hbuf_g       = (u64*)(ws + 262144);            // 4g x 2par x 16KB
  u64* hbuf_l       = (u64*)(ws + 393216);            // 128KB
  float* o1 = (float*)(ws + 1048576);                 // 64MB
  float* o2 = o1 + (size_t)64 * SEQ * HD;             // 64MB

  hipMemsetAsync(ws, 0, 20480, stream);               // flags + stats

  gru_kernel<<<dim3(64), dim3(640), 0, stream>>>(x, gWih, gWhh, gbih, gbhh,
                                                 flags_g, hbuf_g, o1, stats);
  coef_kernel<<<dim3(1), dim3(512), 0, stream>>>(stats, fc1w, fc1b, fc2w, fc2b,
                                                 gam, bet, coef);
  ssr_kernel<<<dim3(8192), dim3(256), 0, stream>>>(o1, coef, ssr_ws, out + 32768);
  lstm_kernel<<<dim3(64), dim3(640), 0, stream>>>(x, lWih, lWhh, lbih, lbhh, ssr_ws,
                                                  flags_l, hbuf_l, o2);
  out_kernel<<<dim3(8192), dim3(256), 0, stream>>>(o2, fc3w, fc3b, out);
}